// Round 2
// baseline (92.870 us; speedup 1.0000x reference)
//
#include <hip/hip_runtime.h>

// Problem constants
constexpr int Cc = 64, Oc = 64, Gc = 16, Ec = 128, Wc = 7;
constexpr int Dc = 4, Nc = 4, Bc = 2, Tc = 512, TTc = 256, FOc = 64;
constexpr float EPSf = 1e-5f, LEAKYf = 0.01f;
// M = B*D*E*t*W = 2*4*128*256*7
constexpr float Minv = 1.0f / 1835008.0f;

// ws layout: raw[2*64*64*256] floats (8 MiB), then partials[2048][8] floats.
// partials[bid][0..3] = mean partial per n; [4..7] = E[y^2] partial per n.

// Fused: stage x once -> unscaled conv to raw, plus BN stat partials.
// LDS x layout transposed: element q (q = t+4, zero pads q<4, q>=516) at
// (q&7)*65 + (q>>3); compute reads become stride-1 across lanes.
__global__ __launch_bounds__(256) void fused_k(const float* __restrict__ x,
                                               const float* __restrict__ wgt,
                                               float* __restrict__ raw,
                                               float* __restrict__ partials) {
  int bid = blockIdx.x;          // (b, g, fo)
  int fo  = bid & 63;
  int g   = (bid >> 6) & 15;
  int b   = bid >> 10;
  int tid = threadIdx.x;

  __shared__ float xs[8 * 520];      // 8 rows (dd*2+f2), transposed layout
  __shared__ float wsm[224];         // [(n*8 + dd*2+f2)*7 + w]
  __shared__ float rowsum[4][4][2];  // [wave][dd][parity] x^2 sums
  __shared__ float QL[8][7];         // x^2 window sums per row per w

  // ---- stage x (float4), accumulate per-row x^2 parity sums in registers ----
  int f2 = tid >> 7;
  int j  = tid & 127;
  float se2p[4], so2p[4];
#pragma unroll
  for (int dd = 0; dd < 4; ++dd) {
    const float4* src = (const float4*)(
        x + ((size_t)((b * Cc + g * Dc + dd) * Ec + 2 * fo + f2)) * Tc);
    float4 v = src[j];
    float* row = &xs[(dd * 2 + f2) * 520];
    int q0 = 4 + 4 * j;
    row[((q0 + 0) & 7) * 65 + ((q0 + 0) >> 3)] = v.x;
    row[((q0 + 1) & 7) * 65 + ((q0 + 1) >> 3)] = v.y;
    row[((q0 + 2) & 7) * 65 + ((q0 + 2) >> 3)] = v.z;
    row[((q0 + 3) & 7) * 65 + ((q0 + 3) >> 3)] = v.w;
    se2p[dd] = v.x * v.x + v.z * v.z;   // even t
    so2p[dd] = v.y * v.y + v.w * v.w;   // odd t
  }
  if (tid < 64) {  // zero pad elements q in {0..3, 516..519}
    int r = tid >> 3, jj = tid & 7;
    int q = (jj < 4) ? jj : (512 + jj);
    xs[r * 520 + (q & 7) * 65 + (q >> 3)] = 0.f;
  }
  if (tid < 224) {  // stage weights for this (g, f-pair)
    int n = tid / 56, rr = tid % 56;
    int dd = rr / 14, r2 = rr % 14;
    int ff = r2 / 7, w = r2 % 7;
    int o = g * Nc + n;
    wsm[tid] = wgt[((size_t)((o * Dc + dd) * Ec + 2 * fo + ff)) * Wc + w];
  }
  // wave-reduce the x^2 parity sums (waves 0,1 hold f2=0; waves 2,3 f2=1)
#pragma unroll
  for (int off = 1; off < 64; off <<= 1) {
#pragma unroll
    for (int dd = 0; dd < 4; ++dd) {
      se2p[dd] += __shfl_xor(se2p[dd], off);
      so2p[dd] += __shfl_xor(so2p[dd], off);
    }
  }
  int lane = tid & 63, wv = tid >> 6;
  if (lane == 0) {
#pragma unroll
    for (int dd = 0; dd < 4; ++dd) {
      rowsum[wv][dd][0] = se2p[dd];
      rowsum[wv][dd][1] = so2p[dd];
    }
  }
  __syncthreads();

  // ---- x^2 window sums Q[r][w] (parity sums + edge corrections) ----
  if (tid < 8) {
    int r = tid, ddi = r >> 1, f2i = r & 1;
    const float* row = &xs[r * 520];
    // t=0 -> q=4 -> 260; t=1 -> 325; t=509 -> 129; t=510 -> 194; t=511 -> 259
    float e0 = row[260], e1 = row[325], e509 = row[129], e510 = row[194],
          e511 = row[259];
    float se2 = rowsum[f2i * 2][ddi][0] + rowsum[f2i * 2 + 1][ddi][0];
    float so2 = rowsum[f2i * 2][ddi][1] + rowsum[f2i * 2 + 1][ddi][1];
    QL[r][0] = so2 - e509 * e509 - e511 * e511;
    QL[r][1] = se2 - e510 * e510;
    QL[r][2] = so2 - e511 * e511;
    QL[r][3] = se2;
    QL[r][4] = so2;
    QL[r][5] = se2 - e0 * e0;
    QL[r][6] = so2 - e1 * e1;
  }
  __syncthreads();

  // ---- conv (unscaled) ----
  int n  = tid >> 6;  // wave = filter-in-group
  int jj = tid & 63;  // tt = 4*jj .. 4*jj+3
  float a0 = 0.f, a1 = 0.f, a2 = 0.f, a3 = 0.f;
#pragma unroll
  for (int r = 0; r < 8; ++r) {
    const float* row = &xs[r * 520];
    float xv[13];
#pragma unroll
    for (int i = 0; i < 13; ++i) {
      int c = 1 + i;  // element 8*jj + c -> addr (c&7)*65 + (c>>3) + jj
      xv[i] = row[(c & 7) * 65 + (c >> 3) + jj];
    }
    const float* wp = &wsm[(n * 8 + r) * 7];
#pragma unroll
    for (int w = 0; w < 7; ++w) {
      float wt = wp[w];
      a0 += xv[w]     * wt;
      a1 += xv[w + 2] * wt;
      a2 += xv[w + 4] * wt;
      a3 += xv[w + 6] * wt;
    }
  }
  int o = g * Nc + n;
  float4 res; res.x = a0; res.y = a1; res.z = a2; res.w = a3;
  *(float4*)(raw + ((size_t)((b * Oc + o) * FOc + fo)) * TTc + 4 * jj) = res;

  // mean partial: sum of this wave's conv outputs over all tt
  float msum = a0 + a1 + a2 + a3;
#pragma unroll
  for (int off = 1; off < 64; off <<= 1) msum += __shfl_xor(msum, off);
  if (jj == 0) partials[bid * 8 + n] = msum;

  // var partial: sum_{r,w} Q[r][w] * w^2  (4 threads, one per n)
  if (tid < 4) {
    float vp = 0.f;
#pragma unroll
    for (int r = 0; r < 8; ++r) {
#pragma unroll
      for (int w = 0; w < 7; ++w) {
        float wt = wsm[(tid * 8 + r) * 7 + w];
        vp += QL[r][w] * wt * wt;
      }
    }
    partials[bid * 8 + 4 + tid] = vp;
  }
}

// Reduce partials -> (a, c) per channel; apply affine + LeakyReLU.
__global__ __launch_bounds__(256) void finish_k(const float* __restrict__ raw,
                                                const float* __restrict__ partials,
                                                const float* __restrict__ gamma,
                                                const float* __restrict__ beta,
                                                float* __restrict__ out) {
  int bid = blockIdx.x;            // (b, o, seg)
  int seg = bid & 15;
  int o   = (bid >> 4) & 63;
  int b   = bid >> 10;
  int tid = threadIdx.x;
  int g = o >> 2, n = o & 3;

  __shared__ float red[2][2];
  __shared__ float sAC[2];

  float mp = 0.f, vp = 0.f;
  if (tid < 128) {
    int b2 = tid >> 6, fo = tid & 63;
    const float* p = &partials[(size_t)(((b2 << 4) | g) << 6 | fo) * 8];
    mp = p[n];
    vp = p[4 + n];
  }
#pragma unroll
  for (int off = 1; off < 64; off <<= 1) {
    mp += __shfl_xor(mp, off);
    vp += __shfl_xor(vp, off);
  }
  int lane = tid & 63, wv = tid >> 6;
  if (lane == 0 && wv < 2) { red[wv][0] = mp; red[wv][1] = vp; }
  __syncthreads();
  if (tid == 0) {
    float mean = (red[0][0] + red[1][0]) * Minv;
    float e2   = (red[0][1] + red[1][1]) * Minv;
    float var  = e2 - mean * mean;          // biased var, matches jnp.var
    float a    = gamma[o] * rsqrtf(var + EPSf);
    sAC[0] = a;
    sAC[1] = 56.0f * (beta[o] - a * mean);  // 2*D*W = 56 elements pooled
  }
  __syncthreads();

  float a = sAC[0], c = sAC[1];
  size_t base = ((size_t)(b * Oc + o)) * (FOc * TTc) + seg * 1024 + tid * 4;
  float4 v = *(const float4*)(raw + base);
  float4 res;
  float r0 = a * v.x + c; res.x = (r0 >= 0.f) ? r0 : LEAKYf * r0;
  float r1 = a * v.y + c; res.y = (r1 >= 0.f) ? r1 : LEAKYf * r1;
  float r2 = a * v.z + c; res.z = (r2 >= 0.f) ? r2 : LEAKYf * r2;
  float r3 = a * v.w + c; res.w = (r3 >= 0.f) ? r3 : LEAKYf * r3;
  *(float4*)(out + base) = res;
}

extern "C" void kernel_launch(void* const* d_in, const int* in_sizes, int n_in,
                              void* d_out, int out_size, void* d_ws, size_t ws_size,
                              hipStream_t stream) {
  (void)in_sizes; (void)n_in; (void)out_size; (void)ws_size;
  const float* x     = (const float*)d_in[0];
  const float* w     = (const float*)d_in[1];
  const float* gamma = (const float*)d_in[2];
  const float* beta  = (const float*)d_in[3];
  float* raw      = (float*)d_ws;                       // 2M floats
  float* partials = raw + (size_t)Bc * Oc * FOc * TTc;  // 2048*8 floats
  fused_k<<<dim3(Bc * Gc * FOc), dim3(256), 0, stream>>>(x, w, raw, partials);
  finish_k<<<dim3(Bc * Oc * 16), dim3(256), 0, stream>>>(raw, partials, gamma,
                                                         beta, (float*)d_out);
}

// Round 3
// 91.484 us; speedup vs baseline: 1.0151x; 1.0151x over previous
//
#include <hip/hip_runtime.h>

// Problem constants
constexpr int Cc = 64, Oc = 64, Gc = 16, Ec = 128, Wc = 7;
constexpr int Dc = 4, Nc = 4, Bc = 2, Tc = 512, TTc = 256, FOc = 64;
constexpr float EPSf = 1e-5f, LEAKYf = 0.01f;
// M = B*D*E*t*W = 2*4*128*256*7
constexpr float Minv = 1.0f / 1835008.0f;

// ws layout: raw[2*64*64*256] floats (8 MiB), then partials[2048][8] floats.
// partials[(b*16+g)*64+fo][0..3] = mean partial per n; [4..7] = E[y^2] partial.

// x LDS layout: per row (16 rows = fo_l*8 + dd*2 + f2), padded q-index
// (q = t + 4; zeros at q<4, q>=516) stored as float4 chunks c = q>>2,
// chunk c at float4-index (c&3)*33 + (c>>2) within the row (132 float4/row).
// Staging writes (consecutive jj) and compute reads (chunks 2j..2j+3) both
// decompose into contiguous-stride-16B lane groups -> conflict-free b128.
__device__ __forceinline__ int FL4(int c) { return (c & 3) * 33 + (c >> 2); }

__global__ __launch_bounds__(256) void fused_k(const float* __restrict__ x,
                                               const float* __restrict__ wgt,
                                               float* __restrict__ raw,
                                               float* __restrict__ partials) {
  int bid = blockIdx.x;          // (b, g, fo2): fo2 = fo>>1
  int fo2 = bid & 31;
  int g   = (bid >> 5) & 15;
  int b   = bid >> 9;
  int t   = threadIdx.x;

  __shared__ float xs[16 * 528];   // 16 rows, chunk-interleaved
  __shared__ float wsm[512];       // [fo_l][lr8][n][8] (w 0..6 + pad)
  __shared__ float QS[16][2];      // per-row x^2 parity sums
  __shared__ float QL[16][7];      // per-row x^2 window sums

  float4* xs4 = (float4*)xs;

  // ---- stage x: 16 rows x 128 float4, fully coalesced global reads ----
#pragma unroll
  for (int k = 0; k < 8; ++k) {
    int idx = t + 256 * k;
    int lr = idx >> 7, jj = idx & 127;
    int fo_l = lr >> 3, dd = (lr >> 1) & 3, f2 = lr & 1;
    const float4* src = (const float4*)(
        x + ((size_t)((b * Cc + g * Dc + dd) * Ec + 4 * fo2 + 2 * fo_l + f2)) * Tc);
    float4 v = src[jj];
    xs4[lr * 132 + FL4(jj + 1)] = v;   // q0 = 4 + 4*jj -> chunk jj+1
  }
  if (t < 32) {  // zero pad chunks 0 and 129 of each row
    int lr = t >> 1;
    int c = (t & 1) ? 129 : 0;
    xs4[lr * 132 + FL4(c)] = make_float4(0.f, 0.f, 0.f, 0.f);
  }
  if (t < 128) {  // stage weights, padded to 8 per (fo_l,lr8,n)
#pragma unroll
    for (int i = 0; i < 4; ++i) {
      int s = t * 4 + i;
      int w = s & 7, n = (s >> 3) & 3, lr8 = (s >> 5) & 7, fo_l = s >> 8;
      int o = g * Nc + n, dd = lr8 >> 1, f = 4 * fo2 + 2 * fo_l + (lr8 & 1);
      wsm[s] = (w < 7) ? wgt[((size_t)((o * Dc + dd) * Ec + f)) * Wc + w] : 0.f;
    }
  }
  __syncthreads();

  // ---- x^2 parity sums per row (16 threads/row, 8 b128 each) ----
  {
    int row = t >> 4, sub = t & 15;
    float se2 = 0.f, so2 = 0.f;
#pragma unroll
    for (int k = 0; k < 8; ++k) {
      int c = 1 + sub + 16 * k;      // real data chunks 1..128
      float4 v = xs4[row * 132 + FL4(c)];
      se2 += v.x * v.x + v.z * v.z;  // q even <=> t even
      so2 += v.y * v.y + v.w * v.w;
    }
#pragma unroll
    for (int off = 1; off < 16; off <<= 1) {
      se2 += __shfl_xor(se2, off);
      so2 += __shfl_xor(so2, off);
    }
    if (sub == 0) { QS[row][0] = se2; QS[row][1] = so2; }
  }

  // ---- conv: each thread = 2 filters (n0,n0+1) x 4 tt ----
  int wv = t >> 6, j = t & 63;
  int fo_l = wv >> 1, n0 = (wv & 1) * 2;
  int fo = fo2 * 2 + fo_l;
  float acc0[4] = {0.f, 0.f, 0.f, 0.f}, acc1[4] = {0.f, 0.f, 0.f, 0.f};
#pragma unroll
  for (int lr8 = 0; lr8 < 8; ++lr8) {
    const float4* rb = xs4 + (fo_l * 8 + lr8) * 132;
    float4 X0 = rb[FL4(2 * j)];
    float4 X1 = rb[FL4(2 * j + 1)];
    float4 X2 = rb[FL4(2 * j + 2)];
    float4 X3 = rb[FL4(2 * j + 3)];
    float xq[16] = {X0.x, X0.y, X0.z, X0.w, X1.x, X1.y, X1.z, X1.w,
                    X2.x, X2.y, X2.z, X2.w, X3.x, X3.y, X3.z, X3.w};
    const float4* wb = (const float4*)&wsm[((fo_l * 8 + lr8) * 4 + n0) * 8];
    float4 Wa0 = wb[0], Wa1 = wb[1], Wb0 = wb[2], Wb1 = wb[3];
    float wA[7] = {Wa0.x, Wa0.y, Wa0.z, Wa0.w, Wa1.x, Wa1.y, Wa1.z};
    float wB[7] = {Wb0.x, Wb0.y, Wb0.z, Wb0.w, Wb1.x, Wb1.y, Wb1.z};
#pragma unroll
    for (int w = 0; w < 7; ++w) {
#pragma unroll
      for (int s = 0; s < 4; ++s) {
        float xv = xq[2 * s + w + 1];  // q = 2*tt + w + 1, tt = 4j+s
        acc0[s] += xv * wA[w];
        acc1[s] += xv * wB[w];
      }
    }
  }
  {  // store unscaled conv
    int o0 = g * Nc + n0;
    float4 r0 = make_float4(acc0[0], acc0[1], acc0[2], acc0[3]);
    float4 r1 = make_float4(acc1[0], acc1[1], acc1[2], acc1[3]);
    *(float4*)(raw + ((size_t)((b * Oc + o0) * FOc + fo)) * TTc + 4 * j) = r0;
    *(float4*)(raw + ((size_t)((b * Oc + o0 + 1) * FOc + fo)) * TTc + 4 * j) = r1;
  }
  {  // mean partials (mean is a linear functional of the conv outputs)
    float ms0 = acc0[0] + acc0[1] + acc0[2] + acc0[3];
    float ms1 = acc1[0] + acc1[1] + acc1[2] + acc1[3];
#pragma unroll
    for (int off = 1; off < 64; off <<= 1) {
      ms0 += __shfl_xor(ms0, off);
      ms1 += __shfl_xor(ms1, off);
    }
    if (j == 0) {
      float* p = &partials[((size_t)((b * Gc + g) * FOc + fo)) * 8];
      p[n0] = ms0;
      p[n0 + 1] = ms1;
    }
  }
  __syncthreads();

  if (t < 16) {  // x^2 window sums from parity sums + edge corrections
    int row = t;
    const float* rowf = &xs[row * 528];
    // chunk 128 (q 512..515) at floats 128..131; chunk 1 (q 4..7) at 132..135
    float e509 = rowf[129], e510 = rowf[130], e511 = rowf[131];
    float e0 = rowf[132], e1 = rowf[133];
    float se2 = QS[row][0], so2 = QS[row][1];
    QL[row][0] = so2 - e509 * e509 - e511 * e511;
    QL[row][1] = se2 - e510 * e510;
    QL[row][2] = so2 - e511 * e511;
    QL[row][3] = se2;
    QL[row][4] = so2;
    QL[row][5] = se2 - e0 * e0;
    QL[row][6] = so2 - e1 * e1;
  }
  __syncthreads();
  if (t < 8) {  // E[y^2] partials: QL . w^2
    int fl = t >> 2, n = t & 3;
    float vp = 0.f;
#pragma unroll
    for (int lr8 = 0; lr8 < 8; ++lr8) {
#pragma unroll
      for (int w = 0; w < 7; ++w) {
        float wt = wsm[((fl * 8 + lr8) * 4 + n) * 8 + w];
        vp += QL[fl * 8 + lr8][w] * wt * wt;
      }
    }
    partials[((size_t)((b * Gc + g) * FOc + fo2 * 2 + fl)) * 8 + 4 + n] = vp;
  }
}

// Reduce partials -> (a, c) per channel; apply affine + LeakyReLU.
__global__ __launch_bounds__(256) void finish_k(const float* __restrict__ raw,
                                                const float* __restrict__ partials,
                                                const float* __restrict__ gamma,
                                                const float* __restrict__ beta,
                                                float* __restrict__ out) {
  int bid = blockIdx.x;            // (b, o, seg)
  int seg = bid & 15;
  int o   = (bid >> 4) & 63;
  int b   = bid >> 10;
  int tid = threadIdx.x;
  int g = o >> 2, n = o & 3;

  __shared__ float red[2][2];
  __shared__ float sAC[2];

  float mp = 0.f, vp = 0.f;
  if (tid < 128) {
    int b2 = tid >> 6, fo = tid & 63;
    const float* p = &partials[(size_t)(((b2 << 4) | g) << 6 | fo) * 8];
    mp = p[n];
    vp = p[4 + n];
  }
#pragma unroll
  for (int off = 1; off < 64; off <<= 1) {
    mp += __shfl_xor(mp, off);
    vp += __shfl_xor(vp, off);
  }
  int lane = tid & 63, wv = tid >> 6;
  if (lane == 0 && wv < 2) { red[wv][0] = mp; red[wv][1] = vp; }
  __syncthreads();
  if (tid == 0) {
    float mean = (red[0][0] + red[1][0]) * Minv;
    float e2   = (red[0][1] + red[1][1]) * Minv;
    float var  = e2 - mean * mean;          // biased var, matches jnp.var
    float a    = gamma[o] * rsqrtf(var + EPSf);
    sAC[0] = a;
    sAC[1] = 56.0f * (beta[o] - a * mean);  // 2*D*W = 56 elements pooled
  }
  __syncthreads();

  float a = sAC[0], c = sAC[1];
  size_t base = ((size_t)(b * Oc + o)) * (FOc * TTc) + seg * 1024 + tid * 4;
  float4 v = *(const float4*)(raw + base);
  float4 res;
  float r0 = a * v.x + c; res.x = (r0 >= 0.f) ? r0 : LEAKYf * r0;
  float r1 = a * v.y + c; res.y = (r1 >= 0.f) ? r1 : LEAKYf * r1;
  float r2 = a * v.z + c; res.z = (r2 >= 0.f) ? r2 : LEAKYf * r2;
  float r3 = a * v.w + c; res.w = (r3 >= 0.f) ? r3 : LEAKYf * r3;
  *(float4*)(out + base) = res;
}

extern "C" void kernel_launch(void* const* d_in, const int* in_sizes, int n_in,
                              void* d_out, int out_size, void* d_ws, size_t ws_size,
                              hipStream_t stream) {
  (void)in_sizes; (void)n_in; (void)out_size; (void)ws_size;
  const float* x     = (const float*)d_in[0];
  const float* w     = (const float*)d_in[1];
  const float* gamma = (const float*)d_in[2];
  const float* beta  = (const float*)d_in[3];
  float* raw      = (float*)d_ws;                       // 2M floats
  float* partials = raw + (size_t)Bc * Oc * FOc * TTc;  // 2048*8 floats
  fused_k<<<dim3(Bc * Gc * 32), dim3(256), 0, stream>>>(x, w, raw, partials);
  finish_k<<<dim3(Bc * Oc * 16), dim3(256), 0, stream>>>(raw, partials, gamma,
                                                         beta, (float*)d_out);
}